// Round 5
// baseline (348.835 us; speedup 1.0000x reference)
//
#include <hip/hip_runtime.h>
#include <cstdint>
#include <cstddef>

// ============================================================================
// MaskGenerator R5:
//  k_wprep : wm/wn fp32 [k][n] -> bf16 [strip][n][k] (Wpack), scratch = d_out
//  k_pre   : fused z + MLP chain + scale + wp/sh + h3 MFMA-A-order pack
//  k_gemm2 : barrier-free dual MFMA GEMM + mask/noise epilogue -> packed u32
//  k_faug2 : FFT + spectral dropout + combine (no mask/noise work)
// PRNG: threefry2x32 partitionable (validated R1-R4).
// ============================================================================

typedef unsigned int u32;
typedef unsigned short u16;

#define Bd 256
#define Ld 512
#define Fd 64
#define Nd 32768            // Ld*Fd

struct U2 { u32 a, b; };

__device__ __forceinline__ u32 rotl32(u32 x, int r){ return (x << r) | (x >> (32 - r)); }

__device__ __forceinline__ U2 tf2x32(u32 k0, u32 k1, u32 x0, u32 x1){
  u32 ks2 = k0 ^ k1 ^ 0x1BD11BDAu;
  x0 += k0; x1 += k1;
#define TFR4(r0,r1,r2,r3) \
  x0 += x1; x1 = rotl32(x1, r0); x1 ^= x0; \
  x0 += x1; x1 = rotl32(x1, r1); x1 ^= x0; \
  x0 += x1; x1 = rotl32(x1, r2); x1 ^= x0; \
  x0 += x1; x1 = rotl32(x1, r3); x1 ^= x0;
  TFR4(13,15,26,6)  x0 += k1;  x1 += ks2 + 1u;
  TFR4(17,29,16,24) x0 += ks2; x1 += k0 + 2u;
  TFR4(13,15,26,6)  x0 += k0;  x1 += k1 + 3u;
  TFR4(17,29,16,24) x0 += k1;  x1 += ks2 + 4u;
  TFR4(13,15,26,6)  x0 += ks2; x1 += k0 + 5u;
#undef TFR4
  U2 r; r.a = x0; r.b = x1; return r;
}

__device__ __forceinline__ u32 rb32(u32 k0, u32 k1, u32 i){
  U2 r = tf2x32(k0, k1, 0u, i);
  return r.a ^ r.b;
}

__device__ __forceinline__ U2 split_key(u32 k0, u32 k1, u32 j){
  return tf2x32(k0, k1, 0u, j);
}

__device__ __forceinline__ float sigmoidf_(float x){ return 1.0f / (1.0f + expf(-x)); }
__device__ __forceinline__ float softplusf_(float x){ return fmaxf(x, 0.0f) + log1pf(expf(-fabsf(x))); }
__device__ __forceinline__ float leakyf_(float x){ return (x > 0.0f) ? x : 0.2f * x; }

__device__ __forceinline__ float erfinvf_(float x){
  float w = -log1pf(-x * x);
  float p;
  if (w < 5.0f){
    w -= 2.5f;
    p =               2.81022636e-08f;
    p = fmaf(p, w,    3.43273939e-07f);
    p = fmaf(p, w,   -3.5233877e-06f);
    p = fmaf(p, w,   -4.39150654e-06f);
    p = fmaf(p, w,    0.00021858087f);
    p = fmaf(p, w,   -0.00125372503f);
    p = fmaf(p, w,   -0.00417768164f);
    p = fmaf(p, w,    0.246640727f);
    p = fmaf(p, w,    1.50140941f);
  } else {
    w = sqrtf(w) - 3.0f;
    p =              -0.000200214257f;
    p = fmaf(p, w,    0.000100950558f);
    p = fmaf(p, w,    0.00134934322f);
    p = fmaf(p, w,   -0.00367342844f);
    p = fmaf(p, w,    0.00573950773f);
    p = fmaf(p, w,   -0.0076224613f);
    p = fmaf(p, w,    0.00943887047f);
    p = fmaf(p, w,    1.00167406f);
    p = fmaf(p, w,    2.83297682f);
  }
  return p * x;
}

__device__ __forceinline__ float uniform_from_bits(u32 bits){
  return __uint_as_float((bits >> 9) | 0x3f800000u) - 1.0f;
}

__device__ __forceinline__ float normal_from_bits(u32 bits){
  float u01 = uniform_from_bits(bits);
  const float lo = -0.99999994f;
  float v = fmaf(u01, 2.0f, lo);
  v = fmaxf(lo, v);
  return 1.41421356f * erfinvf_(v);
}

__device__ __forceinline__ int warp_idx_(int t, int wp, int sh){
  int tps = t + sh;
  int pos = (t >= wp) ? ((tps < Ld - 1) ? tps : (Ld - 1)) : t;
  int neg = ((t >= wp + sh) && (t < Ld + sh)) ? (t - sh) : t;
  return (sh > 0) ? pos : ((sh < 0) ? neg : t);
}

__device__ __forceinline__ u32 pack_bf16_2(float a, float b){
  u32 ua = __float_as_uint(a), ub = __float_as_uint(b);
  u32 ra = (ua + 0x7FFFu + ((ua >> 16) & 1u)) >> 16;
  u32 rb = (ub + 0x7FFFu + ((ub >> 16) & 1u)) >> 16;
  return (ra & 0xFFFFu) | (rb << 16);
}
__device__ __forceinline__ float bf2f(u16 v){
  return __uint_as_float(((u32)v) << 16);
}
__device__ __forceinline__ int rev9_(int k){
  return (int)(__brev((u32)k) >> 23);
}

// ---------------------------------------------------------------------------
// k_wprep: wm/wn fp32 [k=256][n=32768] -> Wpack bf16 [mat][strip=512][n=64][k=256]
// (k-contiguous rows). Wpack lives in d_out (exactly 2*8.39M u16 = 32 MB).
// ---------------------------------------------------------------------------
__global__ __launch_bounds__(256) void k_wprep(const float* __restrict__ wm,
                                               const float* __restrict__ wn,
                                               u16* __restrict__ wpk){
  __shared__ float tile[64 * 260];
  const int mat = blockIdx.x >> 9;
  const int s   = blockIdx.x & 511;
  const int t   = threadIdx.x;
  const float* src = mat ? wn : wm;
  const size_t matoff = (size_t)mat * 8388608;

  #pragma unroll
  for (int r = 0; r < 16; ++r){
    int k  = r * 16 + (t >> 4);
    int n4 = (t & 15) << 2;
    float4 v = *(const float4*)(src + (size_t)k * Nd + s * 64 + n4);
    tile[(n4 + 0) * 260 + k] = v.x;
    tile[(n4 + 1) * 260 + k] = v.y;
    tile[(n4 + 2) * 260 + k] = v.z;
    tile[(n4 + 3) * 260 + k] = v.w;
  }
  __syncthreads();

  const int n = t >> 2, part = t & 3;
  uint4* dst = (uint4*)(wpk + matoff + (size_t)s * 16384 + n * 256 + part * 64);
  #pragma unroll
  for (int u = 0; u < 8; ++u){
    const float* p = &tile[n * 260 + part * 64 + u * 8];
    uint4 q;
    q.x = pack_bf16_2(p[0], p[1]); q.y = pack_bf16_2(p[2], p[3]);
    q.z = pack_bf16_2(p[4], p[5]); q.w = pack_bf16_2(p[6], p[7]);
    dst[u] = q;
  }
}

// ---------------------------------------------------------------------------
// k_pre: per-b fused chain. Block = b. z(64) -> h1(128) -> h2(256) -> h3(256)
// in LDS; emits scl[b][64], wp[b], shv[b], and h3 packed in MFMA-A-frag order:
// h3p[tile=b>>4][chunk=G*4+q][lo=b&15] (uint4 = 8 bf16 k-values).
// ---------------------------------------------------------------------------
__global__ __launch_bounds__(256) void k_pre(
    const float* __restrict__ w1, const float* __restrict__ b1,
    const float* __restrict__ w2, const float* __restrict__ b2,
    const float* __restrict__ w3, const float* __restrict__ b3,
    const float* __restrict__ wsc, const float* __restrict__ bsc,
    const float* __restrict__ p_shift, const float* __restrict__ p_scale,
    uint4* __restrict__ h3p, float* __restrict__ scl,
    int* __restrict__ wp, int* __restrict__ shv)
{
  __shared__ float zs[64], h1s[128], h2s[256], h3s[256];
  const int b = blockIdx.x;
  const int t = threadIdx.x;

  if (t < 64){
    U2 kz = split_key(0u, 42u, 0u);
    zs[t] = normal_from_bits(rb32(kz.a, kz.b, (u32)(b * 64 + t)));
  }
  if (t == 64){
    float s_shift = sigmoidf_(p_shift[0]);
    int wsteps = (int)(51.2f * s_shift);
    U2 kwp = split_key(0u, 42u, 2u);
    U2 k1 = split_key(kwp.a, kwp.b, 0u);
    U2 k2 = split_key(kwp.a, kwp.b, 1u);
    u32 hi = rb32(k1.a, k1.b, (u32)b);
    u32 lo = rb32(k2.a, k2.b, (u32)b);
    u32 span = (u32)(Ld - 2 * wsteps);
    u32 mult = 65536u % span; mult = (mult * mult) % span;
    u32 off = ((hi % span) * mult + (lo % span)) % span;
    wp[b] = wsteps + (int)off;
  }
  if (t == 65){
    float s_shift = sigmoidf_(p_shift[0]);
    int wsteps = (int)(51.2f * s_shift);
    U2 ksh = split_key(0u, 42u, 3u);
    U2 k1 = split_key(ksh.a, ksh.b, 0u);
    U2 k2 = split_key(ksh.a, ksh.b, 1u);
    u32 hi = rb32(k1.a, k1.b, (u32)b);
    u32 lo = rb32(k2.a, k2.b, (u32)b);
    u32 span = (u32)(2 * wsteps + 1);
    u32 mult = 65536u % span; mult = (mult * mult) % span;
    u32 off = ((hi % span) * mult + (lo % span)) % span;
    shv[b] = -wsteps + (int)off;
  }
  __syncthreads();

  if (t < 128){
    float acc = b1[t];
    #pragma unroll 8
    for (int k = 0; k < 64; ++k) acc = fmaf(zs[k], w1[k * 128 + t], acc);
    h1s[t] = leakyf_(acc);
  }
  __syncthreads();
  {
    float acc = b2[t];
    #pragma unroll 8
    for (int k = 0; k < 128; ++k) acc = fmaf(h1s[k], w2[k * 256 + t], acc);
    h2s[t] = leakyf_(acc);
  }
  __syncthreads();
  {
    float acc = b3[t];
    #pragma unroll 8
    for (int k = 0; k < 256; ++k) acc = fmaf(h2s[k], w3[k * 256 + t], acc);
    h3s[t] = leakyf_(acc);
  }
  __syncthreads();
  if (t < 64){
    float acc = bsc[t];
    #pragma unroll 8
    for (int k = 0; k < 256; ++k) acc = fmaf(h3s[k], wsc[k * 64 + t], acc);
    float s_scale = sigmoidf_(p_scale[0]);
    scl[b * 64 + t] = 1.0f + (softplusf_(acc) - 0.5f) * 0.2f * s_scale;
  }
  if (t < 32){
    int c = t;
    int k0 = (c >> 2) * 32 + (c & 3) * 8;
    uint4 q;
    q.x = pack_bf16_2(h3s[k0 + 0], h3s[k0 + 1]);
    q.y = pack_bf16_2(h3s[k0 + 2], h3s[k0 + 3]);
    q.z = pack_bf16_2(h3s[k0 + 4], h3s[k0 + 5]);
    q.w = pack_bf16_2(h3s[k0 + 6], h3s[k0 + 7]);
    h3p[(b >> 4) * 512 + c * 16 + (b & 15)] = q;
  }
}

// ---------------------------------------------------------------------------
// k_gemm2: dual bf16 MFMA GEMM (M=256 b, N=32768, K=256) + mask/noise epilogue.
// Block = 128b x 64n (one Wpack strip), grid (512, 2). B staged once in LDS
// (64 KB, XOR k-group swizzle); A-frags are coalesced uint4 loads from h3p.
// One barrier total. Output: mno[b][n] = packed (bf16 mask*scale, bf16 noise).
// ---------------------------------------------------------------------------
typedef short short8 __attribute__((ext_vector_type(8)));
typedef float f32x4 __attribute__((ext_vector_type(4)));
union Frag { uint4 u; short8 s; };

__global__ __launch_bounds__(256) void k_gemm2(
    const uint4* __restrict__ h3p, const u16* __restrict__ wpk,
    const float* __restrict__ bm, const float* __restrict__ bn,
    const float* __restrict__ scl,
    const float* __restrict__ p_mask, const float* __restrict__ p_noise,
    u32* __restrict__ mno)
{
  __shared__ __align__(16) uint4 Bs[4096];   // [mat(2)][n'(64)][gp(32)] 16B groups

  const int tid  = threadIdx.x;
  const int lane = tid & 63;
  const int w    = tid >> 6;
  const int q    = lane >> 4;
  const int lo   = lane & 15;
  const int bx   = blockIdx.x;          // n-strip (64 wide)
  const int b0   = blockIdx.y << 7;     // 128 b rows
  const int wr   = (w & 1) << 6;        // wave m offset 0/64
  const int wc   = (w >> 1) << 5;       // wave n offset 0/32

  // ---- stage B once (both matrices), swizzled ----
  #pragma unroll
  for (int i = 0; i < 16; ++i){
    int slot = i * 256 + tid;
    int mat  = slot >> 11;
    int np   = (slot >> 5) & 63;
    int gp   = slot & 31;
    int gi   = gp ^ (np & 7);
    Bs[slot] = *(const uint4*)(wpk + (size_t)mat * 8388608 +
                               (size_t)bx * 16384 + np * 256 + gi * 8);
  }
  __syncthreads();

  f32x4 accm[4][2], accn[4][2];
  #pragma unroll
  for (int i = 0; i < 4; ++i)
    #pragma unroll
    for (int j = 0; j < 2; ++j){ accm[i][j] = (f32x4)0.0f; accn[i][j] = (f32x4)0.0f; }

  const int tbase = (blockIdx.y << 3) + ((w & 1) << 2);   // h3p tile base

  for (int G = 0; G < 8; ++G){
    Frag af[4], bfm[2], bfn[2];
    #pragma unroll
    for (int mt = 0; mt < 4; ++mt)
      af[mt].u = h3p[(tbase + mt) * 512 + (G * 4 + q) * 16 + lo];
    #pragma unroll
    for (int nt = 0; nt < 2; ++nt){
      int np = wc + nt * 16 + lo;
      int gp = (G * 4 + q) ^ (np & 7);
      bfm[nt].u = Bs[np * 32 + gp];
      bfn[nt].u = Bs[2048 + np * 32 + gp];
    }
    #pragma unroll
    for (int mt = 0; mt < 4; ++mt){
      #pragma unroll
      for (int nt = 0; nt < 2; ++nt){
        accm[mt][nt] = __builtin_amdgcn_mfma_f32_16x16x32_bf16(af[mt].s, bfm[nt].s, accm[mt][nt], 0, 0, 0);
        accn[mt][nt] = __builtin_amdgcn_mfma_f32_16x16x32_bf16(af[mt].s, bfn[nt].s, accn[mt][nt], 0, 0, 0);
      }
    }
  }

  // ---- epilogue: mask*scale + noise term, packed store ----
  float s_mask  = sigmoidf_(p_mask[0]);
  float s_noise = sigmoidf_(p_noise[0]);
  U2 knk = split_key(0u, 42u, 1u);

  #pragma unroll
  for (int nt = 0; nt < 2; ++nt){
    int f = wc + nt * 16 + lo;           // n within strip == feature context
    int n = (bx << 6) + f;
    float bmv = bm[n];
    float bnv = bn[n];
    #pragma unroll
    for (int mt = 0; mt < 4; ++mt){
      #pragma unroll
      for (int r = 0; r < 4; ++r){
        int b = b0 + wr + mt * 16 + q * 4 + r;
        float maskv = sigmoidf_(accm[mt][nt][r] + bmv);
        maskv = 1.0f - (1.0f - maskv) * s_mask * 0.3f;
        float mne = maskv * scl[b * 64 + (n & 63)];
        float nmag = softplusf_(accn[mt][nt][r] + bnv);
        float nz = normal_from_bits(rb32(knk.a, knk.b, (u32)(b * Nd + n)));
        float noise = nz * nmag * s_noise * 0.05f;
        mno[(size_t)b * Nd + n] = pack_bf16_2(mne, noise);
      }
    }
  }
}

// ---------------------------------------------------------------------------
// k_faug2: packed real-pair FFT + spectral dropout + inverse + combine.
// (identical FFT structure to validated R4 k_faug; epilogue now trivial)
// ---------------------------------------------------------------------------
#define PITCH 529
__device__ __forceinline__ int lphys(int t){ return t + (t >> 5); }

__global__ __launch_bounds__(256, 4) void k_faug2(
    const float* __restrict__ x,
    const u32* __restrict__ mno,
    const int* __restrict__ wp, const int* __restrict__ shv,
    const float* __restrict__ p_shift,
    float* __restrict__ out)
{
  __shared__ float SR[8 * PITCH];
  __shared__ float SI[8 * PITCH];
  __shared__ float2 tw[256];

  const int tid = threadIdx.x;
  const int b   = blockIdx.x >> 2;
  const int f0  = (blockIdx.x & 3) << 4;

  float s_shift = sigmoidf_(p_shift[0]);
  float s_mix   = 1.0f - s_shift;
  float ratio   = fminf(s_mix * 0.1f, 0.5f);
  float wa = 1.0f - s_mix - s_shift;
  wa = fminf(fmaxf(wa, 0.1f), 0.8f);
  float wb = s_mix * 0.5f;
  float wc = s_shift * 0.5f;
  float tot = wa + wb + wc;
  wa /= tot; wb /= tot; wc /= tot;
  bool pass = (s_mix < 0.01f);

  U2 kf = split_key(0u, 42u, 4u);
  const int wpb = wp[b];
  const int shb = shv[b];

  {
    float ang = -6.283185307179586f * ((float)tid / 512.0f);
    tw[tid] = make_float2(cosf(ang), sinf(ang));
  }

  const float* xb = x + (size_t)b * Nd;
  #pragma unroll
  for (int s = 0; s < 8; ++s){
    int qq = (s << 8) + tid;
    int t  = qq >> 2;
    int f4 = qq & 3;
    float4 v = *(const float4*)(xb + t * 64 + f0 + (f4 << 2));
    int j = f4 << 1;
    int pt = lphys(t);
    SR[j * PITCH + pt]       = v.x;  SI[j * PITCH + pt]       = v.y;
    SR[(j + 1) * PITCH + pt] = v.z;  SI[(j + 1) * PITCH + pt] = v.w;
  }
  __syncthreads();

  // forward DIF (natural -> bitrev)
  for (int s = 9; s >= 1; --s){
    int half = 1 << (s - 1);
    #pragma unroll
    for (int it = 0; it < 8; ++it){
      int j  = it;
      int bi = tid;
      int pos = bi & (half - 1);
      int g = bi >> (s - 1);
      int i1 = (g << s) + pos;
      int i2 = i1 + half;
      int a1 = j * PITCH + lphys(i1);
      int a2 = j * PITCH + lphys(i2);
      float ur = SR[a1], ui = SI[a1];
      float vr = SR[a2], vi = SI[a2];
      SR[a1] = ur + vr; SI[a1] = ui + vi;
      float dr = ur - vr, di = ui - vi;
      float2 wv = tw[pos << (9 - s)];
      SR[a2] = dr * wv.x - di * wv.y;
      SI[a2] = dr * wv.y + di * wv.x;
    }
    __syncthreads();
  }

  // masked Hermitian repack at natural frequency k
  #pragma unroll
  for (int it = 0; it < 8; ++it){
    int j = it;
    int k = tid;
    int nItr = (k == 0) ? 2 : 1;
    for (int e = 0; e < nItr; ++e){
      int kk = (e == 0) ? k : 256;
      int nk = (512 - kk) & 511;
      int pk = rev9_(kk), pn = rev9_(nk);
      int ak = j * PITCH + lphys(pk);
      int an = j * PITCH + lphys(pn);
      float zkr = SR[ak], zki = SI[ak];
      float znr = SR[an], zni = SI[an];
      float X0r = 0.5f * (zkr + znr), X0i = 0.5f * (zki - zni);
      float X1r = 0.5f * (zki + zni), X1i = 0.5f * (znr - zkr);
      int fA = f0 + (j << 1);
      u32 ck = (u32)((b * Ld + kk) * Fd + fA);
      u32 cn = (u32)((b * Ld + nk) * Fd + fA);
      float k0a = (uniform_from_bits(rb32(kf.a, kf.b, ck))      > ratio) ? 1.0f : 0.0f;
      float k0b = (uniform_from_bits(rb32(kf.a, kf.b, cn))      > ratio) ? 1.0f : 0.0f;
      float k1a = (uniform_from_bits(rb32(kf.a, kf.b, ck + 1u)) > ratio) ? 1.0f : 0.0f;
      float k1b = (uniform_from_bits(rb32(kf.a, kf.b, cn + 1u)) > ratio) ? 1.0f : 0.0f;
      float m0 = 0.5f * (k0a + k0b);
      float m1 = 0.5f * (k1a + k1b);
      SR[ak] = m0 * X0r - m1 * X1i;
      SI[ak] = m0 * X0i + m1 * X1r;
      SR[an] = m0 * X0r + m1 * X1i;
      SI[an] = m1 * X1r - m0 * X0i;
    }
  }
  __syncthreads();

  // inverse DIT (bitrev -> natural)
  for (int s = 1; s <= 9; ++s){
    int half = 1 << (s - 1);
    #pragma unroll
    for (int it = 0; it < 8; ++it){
      int j  = it;
      int bi = tid;
      int pos = bi & (half - 1);
      int g = bi >> (s - 1);
      int i1 = (g << s) + pos;
      int i2 = i1 + half;
      int a1 = j * PITCH + lphys(i1);
      int a2 = j * PITCH + lphys(i2);
      float2 wv = tw[pos << (9 - s)];
      float vr = SR[a2], vi = SI[a2];
      float tx_ = vr * wv.x + vi * wv.y;
      float ty_ = vi * wv.x - vr * wv.y;
      float ur = SR[a1], ui = SI[a1];
      SR[a1] = ur + tx_; SI[a1] = ui + ty_;
      SR[a2] = ur - tx_; SI[a2] = ui - ty_;
    }
    __syncthreads();
  }

  // combine epilogue
  const float inv512 = 1.0f / 512.0f;
  const u32* mb = mno + (size_t)b * Nd;
  float* ob = out + (size_t)b * Nd;
  #pragma unroll
  for (int s = 0; s < 8; ++s){
    int qq = (s << 8) + tid;
    int t  = qq >> 2;
    int f4 = qq & 3;
    int f  = f0 + (f4 << 2);
    int j  = f4 << 1;
    int pt = lphys(t);
    int nidx = t * 64 + f;
    float4 xv = *(const float4*)(xb + nidx);
    int wi = warp_idx_(t, wpb, shb);
    float4 wv = *(const float4*)(xb + wi * 64 + f);
    uint4 mv = *(const uint4*)(mb + nidx);
    float fr[4];
    fr[0] = SR[j * PITCH + pt] * inv512;
    fr[1] = SI[j * PITCH + pt] * inv512;
    fr[2] = SR[(j + 1) * PITCH + pt] * inv512;
    fr[3] = SI[(j + 1) * PITCH + pt] * inv512;
    const float xvv[4] = {xv.x, xv.y, xv.z, xv.w};
    const float wvv[4] = {wv.x, wv.y, wv.z, wv.w};
    const u32 mvv[4] = {mv.x, mv.y, mv.z, mv.w};
    float o[4];
    #pragma unroll
    for (int c = 0; c < 4; ++c){
      float mne = bf2f((u16)(mvv[c] & 0xFFFFu));
      float noi = bf2f((u16)(mvv[c] >> 16));
      float aug = fmaf(xvv[c], mne, noi);
      float fq = pass ? xvv[c] : fr[c];
      o[c] = aug * wa + fq * wb + wvv[c] * wc;
    }
    *(float4*)(ob + nidx) = make_float4(o[0], o[1], o[2], o[3]);
  }
}

// ---------------------------------------------------------------------------
extern "C" void kernel_launch(void* const* d_in, const int* in_sizes, int n_in,
                              void* d_out, int out_size, void* d_ws, size_t ws_size,
                              hipStream_t stream)
{
  (void)in_sizes; (void)n_in; (void)out_size; (void)ws_size;
  const float* x   = (const float*)d_in[0];
  const float* w1  = (const float*)d_in[2];
  const float* b1  = (const float*)d_in[3];
  const float* w2  = (const float*)d_in[4];
  const float* b2  = (const float*)d_in[5];
  const float* w3  = (const float*)d_in[6];
  const float* b3  = (const float*)d_in[7];
  const float* wm  = (const float*)d_in[8];
  const float* bm  = (const float*)d_in[9];
  const float* wn  = (const float*)d_in[10];
  const float* bn  = (const float*)d_in[11];
  const float* wsc = (const float*)d_in[12];
  const float* bsc = (const float*)d_in[13];
  const float* pm  = (const float*)d_in[14];
  const float* pn  = (const float*)d_in[15];
  const float* psh = (const float*)d_in[16];
  const float* psc = (const float*)d_in[17];
  float* out = (float*)d_out;
  char* ws = (char*)d_ws;

  // ws layout
  int*   wp   = (int*)  (ws + 0);         // 1 KB
  int*   shv  = (int*)  (ws + 1024);      // 1 KB
  float* scl  = (float*)(ws + 2048);      // 64 KB
  uint4* h3p  = (uint4*)(ws + 67584);     // 128 KB
  u32*   mno  = (u32*)  (ws + 1048576);   // 32 MB
  // Wpack scratch lives in d_out (32 MB exactly); overwritten by k_faug2 last.
  u16*   wpk  = (u16*)d_out;

  k_wprep<<<dim3(1024),   dim3(256), 0, stream>>>(wm, wn, wpk);
  k_pre  <<<dim3(256),    dim3(256), 0, stream>>>(w1, b1, w2, b2, w3, b3, wsc, bsc,
                                                  psh, psc, h3p, scl, wp, shv);
  k_gemm2<<<dim3(512, 2), dim3(256), 0, stream>>>(h3p, wpk, bm, bn, scl, pm, pn, mno);
  k_faug2<<<dim3(1024),   dim3(256), 0, stream>>>(x, mno, wp, shv, psh, out);
}